// Round 3
// baseline (921.275 us; speedup 1.0000x reference)
//
#include <hip/hip_runtime.h>
#include <hip/hip_bf16.h>
#include <math.h>

typedef unsigned short u16;
typedef __attribute__((ext_vector_type(8))) short bf16x8;
typedef __attribute__((ext_vector_type(4))) float f32x4;
typedef __attribute__((ext_vector_type(4))) u16 u16x4;

#define DEVI static __device__ __forceinline__

DEVI float bf2f(u16 h){ union{unsigned u; float f;} v; v.u=((unsigned)h)<<16; return v.f; }
DEVI u16 f2bf(float x){ union{float f; unsigned u;} v; v.f=x; unsigned r=v.u+0x7fffu+((v.u>>16)&1u); return (u16)(r>>16); }
DEVI void split2(float x, u16 &h, u16 &l){ h=f2bf(x); l=f2bf(x-bf2f(h)); }
DEVI float geluf(float x){ return 0.5f*x*(1.0f+erff(x*0.70710678118654752f)); }

#define GLD16(g,s) __builtin_amdgcn_global_load_lds((const __attribute__((address_space(1))) void*)(g), (__attribute__((address_space(3))) void*)(s), 16, 0, 0)

// ---------------- K0: LN stats (mean/rstd over C) for the 3 [B,C,N] inputs ----------------
__global__ void ln_stats_k(const float* __restrict__ x0, const float* __restrict__ x1,
                           const float* __restrict__ x2, float* __restrict__ muS,
                           float* __restrict__ rsS)
{
  const int inp = blockIdx.y;
  const float* x = inp==0?x0:(inp==1?x1:x2);
  const int T0 = blockIdx.x*64;            // token base = b*1024 + n0
  const int b = T0>>10, n0 = T0&1023;
  const int tid = threadIdx.x;
  const int n = tid&63, part = tid>>6;
  const float* base = x + ((size_t)b*768)*1024 + n0 + n;
  float s=0.f, s2=0.f;
  for (int c=part;c<768;c+=4){ float v = base[(size_t)c*1024]; s+=v; s2+=v*v; }
  __shared__ float r1[256], r2[256];
  r1[tid]=s; r2[tid]=s2; __syncthreads();
  if (tid<64){
    s = r1[tid]+r1[tid+64]+r1[tid+128]+r1[tid+192];
    s2= r2[tid]+r2[tid+64]+r2[tid+128]+r2[tid+192];
    float mu = s*(1.f/768.f);
    float var = s2*(1.f/768.f)-mu*mu;
    muS[inp*16384+T0+tid]=mu;
    rsS[inp*16384+T0+tid]=rsqrtf(var+1e-5f);
  }
}

// ------------- K1: apply LN + split to bf16 pairs + transpose [C,N] -> [N,C] -------------
__global__ void ln_apply_k(const float* __restrict__ x, const float* __restrict__ muS,
                           const float* __restrict__ rsS, const float* __restrict__ g,
                           const float* __restrict__ be, u16* __restrict__ Ah,
                           u16* __restrict__ Al, int inp)
{
  const int b = blockIdx.y;
  const int gx = blockIdx.x;               // 24 c-tiles x 32 n-tiles
  const int c0=(gx%24)*32, n0=(gx/24)*32;
  const int tid=threadIdx.x;
  __shared__ u16 Hh[32][33], Hl[32][33];
  const int nl=tid&31, cp=tid>>5;
  const int tok = b*1024 + n0 + nl;
  const float mu = muS[inp*16384+tok], rs = rsS[inp*16384+tok];
  #pragma unroll
  for (int i=0;i<4;i++){
    int cl = cp + i*8;
    int c = c0 + cl;
    float v = x[((size_t)(b*768+c))*1024 + n0 + nl];
    float y = (v-mu)*rs*g[c]+be[c];
    u16 h,l; split2(y,h,l);
    Hh[cl][nl]=h; Hl[cl][nl]=l;
  }
  __syncthreads();
  const int wn = tid>>3, wc=(tid&7)*4;
  u16x4 vh, vl;
  #pragma unroll
  for (int j=0;j<4;j++){ vh[j]=Hh[wc+j][wn]; vl[j]=Hl[wc+j][wn]; }
  size_t o = ((size_t)(b*1024+n0+wn))*768 + c0 + wc;
  *(u16x4*)(Ah+o)=vh; *(u16x4*)(Al+o)=vl;
}

// ---------------- weight split: fp32 [768,768] -> hi/lo bf16 ----------------
__global__ void wsplit_k(const float* __restrict__ w0,const float* __restrict__ w1,
                         const float* __restrict__ w2,const float* __restrict__ wpk,
                         u16* __restrict__ wh, u16* __restrict__ wl)
{
  const int ws = blockIdx.y;
  const float* w = ws==0?w0:(ws==1?w1:(ws==2?w2:wpk));
  int i = blockIdx.x*256+threadIdx.x;
  u16 h,l; split2(w[i],h,l);
  wh[(size_t)ws*589824+i]=h; wl[(size_t)ws*589824+i]=l;
}

// ------------- transpose t pairs: [B*1024,768] -> per-batch [768,1024] -------------
__global__ void tr_pairs_k(const u16* __restrict__ Sh, const u16* __restrict__ Sl,
                           u16* __restrict__ Dh, u16* __restrict__ Dl)
{
  const int b = blockIdx.y;
  const int gx = blockIdx.x;
  const int c0=(gx%24)*32, n0=(gx/24)*32;
  const int tid=threadIdx.x;
  __shared__ u16 Th[32][33], Tl[32][33];
  const int cl=tid&31, np=tid>>5;
  #pragma unroll
  for (int i=0;i<4;i++){
    int nl = np + i*8;
    size_t o = ((size_t)(b*1024+n0+nl))*768 + c0 + cl;
    Th[cl][nl]=Sh[o]; Tl[cl][nl]=Sl[o];
  }
  __syncthreads();
  const int nl2=tid&31, cp2=tid>>5;
  #pragma unroll
  for (int i=0;i<4;i++){
    int cl2 = cp2 + i*8;
    size_t o = ((size_t)b*786432) + (size_t)(c0+cl2)*1024 + n0 + nl2;
    Dh[o]=Th[cl2][nl2]; Dl[o]=Tl[cl2][nl2];
  }
}

// ---- softmax over rows of S chunk [8*1024, 1024] fp32, writing bf16 pairs IN PLACE ----
// out row layout: [row][ hi x1024 | lo x1024 ] u16  (same 4KiB as the fp32 row)
__global__ void softmax_k(float* __restrict__ S)
{
  const long row = blockIdx.x;
  const int tid=threadIdx.x;
  const int lane=tid&63, wid=tid>>6;
  float4 v4 = *(const float4*)(S + row*1024 + tid*4);
  float m = fmaxf(fmaxf(v4.x,v4.y),fmaxf(v4.z,v4.w));
  for (int o=1;o<64;o<<=1) m = fmaxf(m, __shfl_xor(m,o,64));
  __shared__ float red[4]; __shared__ float red2[4];
  if (lane==0) red[wid]=m;
  __syncthreads();
  m = fmaxf(fmaxf(red[0],red[1]),fmaxf(red[2],red[3]));
  float e0=__expf(v4.x-m), e1=__expf(v4.y-m), e2=__expf(v4.z-m), e3=__expf(v4.w-m);
  float s = e0+e1+e2+e3;
  for (int o=1;o<64;o<<=1) s += __shfl_xor(s,o,64);
  if (lane==0) red2[wid]=s;
  __syncthreads();                          // all S-row reads complete before this point
  s = red2[0]+red2[1]+red2[2]+red2[3];
  float inv = 1.f/s;
  u16x4 h4,l4;
  u16 h,l;
  split2(e0*inv,h,l); h4[0]=h; l4[0]=l;
  split2(e1*inv,h,l); h4[1]=h; l4[1]=l;
  split2(e2*inv,h,l); h4[2]=h; l4[2]=l;
  split2(e3*inv,h,l); h4[3]=h; l4[3]=l;
  u16* base = (u16*)S + row*2048;
  *(u16x4*)(base + tid*4)        = h4;
  *(u16x4*)(base + 1024 + tid*4) = l4;
}

// -------- x_middle = (r+t) + mid-reorder (tile transpose of mid per batch) --------
__global__ void midtr_k(const float* __restrict__ mid, const u16* __restrict__ rh,
                        const u16* __restrict__ rl, const u16* __restrict__ th,
                        const u16* __restrict__ tl, float* __restrict__ xm)
{
  const int b=blockIdx.y;
  const int gx=blockIdx.x;
  const int c0=(gx%24)*32, n0=(gx/24)*32;
  const int tid=threadIdx.x;
  __shared__ float T[32][33];
  const int cl=tid&31, np=tid>>5;
  #pragma unroll
  for (int i=0;i<4;i++){
    int nl=np+i*8;
    T[cl][nl] = mid[((size_t)b*786432)+(size_t)(n0+nl)*768 + c0+cl];
  }
  __syncthreads();
  const int nl2=tid&31, cp2=tid>>5;
  #pragma unroll
  for (int i=0;i<4;i++){
    int cl2=cp2+i*8;
    size_t j = (size_t)(c0+cl2)*1024 + n0+nl2;
    size_t gi = (size_t)b*786432 + j;
    float rv = bf2f(rh[gi])+bf2f(rl[gi]);
    float tv = bf2f(th[gi])+bf2f(tl[gi]);
    xm[gi] = rv+tv+T[cl2][nl2];
  }
}

// -------- row LN (contiguous C) + split -> xm pairs --------
__global__ void ln_rows_k(const float* __restrict__ x, const float* __restrict__ g,
                          const float* __restrict__ be, u16* __restrict__ Oh, u16* __restrict__ Ol)
{
  const long row=blockIdx.x;
  const int tid=threadIdx.x;
  const float* xr = x + row*768;
  float v0=xr[tid], v1=xr[tid+256], v2=xr[tid+512];
  float s=v0+v1+v2, s2=v0*v0+v1*v1+v2*v2;
  for (int o=1;o<64;o<<=1){ s+=__shfl_xor(s,o,64); s2+=__shfl_xor(s2,o,64); }
  __shared__ float rA[4]; __shared__ float rB[4];
  const int lane=tid&63, wid=tid>>6;
  if(lane==0){rA[wid]=s;rB[wid]=s2;}
  __syncthreads();
  s=rA[0]+rA[1]+rA[2]+rA[3]; s2=rB[0]+rB[1]+rB[2]+rB[3];
  float mu=s*(1.f/768.f), var=s2*(1.f/768.f)-mu*mu, rs=rsqrtf(var+1e-5f);
  u16 h,l;
  float y0=(v0-mu)*rs*g[tid]+be[tid];         split2(y0,h,l); Oh[row*768+tid]=h;     Ol[row*768+tid]=l;
  float y1=(v1-mu)*rs*g[tid+256]+be[tid+256]; split2(y1,h,l); Oh[row*768+tid+256]=h; Ol[row*768+tid+256]=l;
  float y2=(v2-mu)*rs*g[tid+512]+be[tid+512]; split2(y2,h,l); Oh[row*768+tid+512]=h; Ol[row*768+tid+512]=l;
}

// ---------------- 3-term split-fp32 GEMM: D = (Ah+Al)·(Bh+Bl)^T, 128x128 tile ----------------
// A: rows k-contig with row stride lda; B: rows k-contig with row stride ldb (elems).
// Output row addressing: o = batch*oBat + (r>>10)*oBat + (r&1023)*ldo + cc  (r<1024 when batched)
// EPI: 0 = pairs+bias, 1 = f32*scale, 2 = f32, 3 = final fused epilogue -> dout
template<int EPI>
__launch_bounds__(256,2)
__global__ void gemm3_k(const u16* __restrict__ Ah, const u16* __restrict__ Al, long aBat, int lda,
                        const u16* __restrict__ Bh, const u16* __restrict__ Bl, long bBat, int ldb,
                        int K, int tilesM, int ldo, long oBat, float scaleV,
                        const float* __restrict__ bias,
                        u16* __restrict__ Oh, u16* __restrict__ Ol,
                        float* __restrict__ outF,
                        const float* __restrict__ xmid,
                        const u16* __restrict__ rhp, const u16* __restrict__ rlp,
                        const u16* __restrict__ thp, const u16* __restrict__ tlp,
                        float* __restrict__ dout)
{
  __shared__ u16 sm[16384];                // Ah|Al|Bh|Bl, each 128x32 bf16
  u16* sAh=sm; u16* sAl=sm+4096; u16* sBh=sm+8192; u16* sBl=sm+12288;
  const int tid=threadIdx.x, lane=tid&63, wid=tid>>6;
  const int wm=(wid&1)*64, wn=(wid>>1)*64;
  const int tm = (blockIdx.x % tilesM)*128;
  const int tn = (blockIdx.x / tilesM)*128;
  const int batch = blockIdx.y;
  const u16* gAh = Ah + (long)batch*aBat + (long)tm*lda;
  const u16* gAl = Al + (long)batch*aBat + (long)tm*lda;
  const u16* gBh = Bh + (long)batch*bBat + (long)tn*ldb;
  const u16* gBl = Bl + (long)batch*bBat + (long)tn*ldb;
  f32x4 acc[4][4];
  #pragma unroll
  for(int i=0;i<4;i++)
    #pragma unroll
    for(int j=0;j<4;j++) acc[i][j]=(f32x4){0.f,0.f,0.f,0.f};
  const int frow=lane&15, fko=(lane>>4)<<3;
  const int nkt=K>>5;
  for(int kt=0;kt<nkt;kt++){
    const int k0=kt<<5;
    __syncthreads();
    #pragma unroll
    for(int is=0;is<2;is++){
      int idx=is*256+tid;
      int mm=idx>>2, ko=(idx&3)<<3;
      long goA=(long)mm*lda + k0 + ko;
      long goB=(long)mm*ldb + k0 + ko;
      int so=(idx & ~63)*8;                // wave-uniform LDS base (ushorts)
      GLD16(gAh+goA, sAh+so);
      GLD16(gAl+goA, sAl+so);
      GLD16(gBh+goB, sBh+so);
      GLD16(gBl+goB, sBl+so);
    }
    __syncthreads();
    bf16x8 fbh[4], fbl[4];
    #pragma unroll
    for(int j=0;j<4;j++){
      int off=(wn+j*16+frow)*32+fko;
      fbh[j]=*(const bf16x8*)(sBh+off);
      fbl[j]=*(const bf16x8*)(sBl+off);
    }
    #pragma unroll
    for(int i=0;i<4;i++){
      int off=(wm+i*16+frow)*32+fko;
      bf16x8 fah=*(const bf16x8*)(sAh+off);
      bf16x8 fal=*(const bf16x8*)(sAl+off);
      #pragma unroll
      for(int j=0;j<4;j++){
        acc[i][j]=__builtin_amdgcn_mfma_f32_16x16x32_bf16(fah,fbh[j],acc[i][j],0,0,0);
        acc[i][j]=__builtin_amdgcn_mfma_f32_16x16x32_bf16(fah,fbl[j],acc[i][j],0,0,0);
        acc[i][j]=__builtin_amdgcn_mfma_f32_16x16x32_bf16(fal,fbh[j],acc[i][j],0,0,0);
      }
    }
  }
  const int r0 = tm+wm+((lane>>4)<<2);
  const int c0 = tn+wn+(lane&15);
  #pragma unroll
  for(int i=0;i<4;i++){
    #pragma unroll
    for(int q=0;q<4;q++){
      int r = r0 + i*16 + q;
      #pragma unroll
      for(int j=0;j<4;j++){
        int cc = c0 + j*16;
        float v = acc[i][j][q];
        long o = (long)batch*oBat + (long)(r>>10)*oBat + (long)(r&1023)*ldo + cc;
        if constexpr (EPI==0){
          v += bias[cc];
          u16 h,l; split2(v,h,l);
          Oh[o]=h; Ol[o]=l;
        } else if constexpr (EPI==1){
          outF[o] = v*scaleV;
        } else if constexpr (EPI==2){
          outF[o] = v;
        } else {
          float lin = v + bias[cc];
          float xmv = xmid[o];
          float rv = bf2f(rhp[o])+bf2f(rlp[o]);
          float tv = bf2f(thp[o])+bf2f(tlp[o]);
          float xs=rv+tv, xmu=rv*tv;
          dout[o] = (geluf(xs)+geluf(xmu))*(xmv+lin);
        }
      }
    }
  }
}

extern "C" void kernel_launch(void* const* d_in, const int* in_sizes, int n_in,
                              void* d_out, int out_size, void* d_ws, size_t ws_size,
                              hipStream_t stream)
{
  const float* x_rgb=(const float*)d_in[0];
  const float* x_tir=(const float*)d_in[1];
  const float* x_bef=(const float*)d_in[2];
  const float* w0=(const float*)d_in[3];
  const float* b0=(const float*)d_in[4];
  const float* w1=(const float*)d_in[5];
  const float* b1=(const float*)d_in[6];
  const float* w2=(const float*)d_in[7];
  const float* b2=(const float*)d_in[8];
  const float* lng=(const float*)d_in[9];
  const float* lnb=(const float*)d_in[10];
  const float* wpk=(const float*)d_in[11];
  const float* bp=(const float*)d_in[12];
  float* out=(float*)d_out;

  char* wsb=(char*)d_ws;
  size_t off=0;
  auto alloc=[&](size_t bytes)->char*{ char* p=wsb+off; off=(off+bytes+255)&~(size_t)255; return p; };

  const long PAIRE = (long)16384*768;             // elements per bf16 plane (24 MiB)
  float* muS = (float*)alloc(3*16384*4);
  float* rsS = (float*)alloc(3*16384*4);
  u16* wh = (u16*)alloc(4*589824*2);
  u16* wl = (u16*)alloc(4*589824*2);
  // stageA (48 MiB): LN-staging pairs -> t^T pairs -> LN(x_middle) pairs
  char* stageA = alloc((size_t)2*PAIRE*2);
  u16* sAh=(u16*)stageA;      u16* sAl=sAh+PAIRE;
  u16* tTh=sAh;               u16* tTl=sAh+PAIRE;
  u16* xmh=sAh;               u16* xml=sAh+PAIRE;
  u16* rh=(u16*)alloc(PAIRE*2); u16* rl=(u16*)alloc(PAIRE*2);
  u16* th=(u16*)alloc(PAIRE*2); u16* tl=(u16*)alloc(PAIRE*2);
  // f/mid (48 MiB): batch-interleaved {fh_b[1024x768], fl_b[1024x768]} -> mid_b fp32 in place
  char* fmid = alloc((size_t)2*PAIRE*2);
  u16* fb=(u16*)fmid;
  float* midf=(float*)fmid;
  // S/P chunk (32 MiB used of 48) -> x_middle fp32 (48 MiB)
  char* SPx = alloc((size_t)2*PAIRE*2);
  float* Sf=(float*)SPx;
  u16* Pu=(u16*)SPx;
  float* xmf=(float*)SPx;

  if (off > ws_size){                              // workspace too small: fail cleanly
    hipMemsetAsync(d_out, 0, (size_t)out_size*4, stream);
    return;
  }

  const float SC = 0.03608439182435161f;          // 1/sqrt(768)
  dim3 blk(256);

  wsplit_k<<<dim3(2304,4),blk,0,stream>>>(w0,w1,w2,wpk,wh,wl);
  ln_stats_k<<<dim3(256,3),blk,0,stream>>>(x_rgb,x_tir,x_bef,muS,rsS);

  // r = LN(x_rgb) @ w0^T + b0        [16384,768] pairs
  ln_apply_k<<<dim3(768,16),blk,0,stream>>>(x_rgb,muS,rsS,lng,lnb,sAh,sAl,0);
  gemm3_k<0><<<dim3(128*6,1),blk,0,stream>>>(sAh,sAl,0,768, wh,wl,0,768, 768,128,768,786432, 0.f,
      b0, rh,rl, nullptr, nullptr,nullptr,nullptr,nullptr,nullptr,nullptr);
  // t = LN(x_tir) @ w1^T + b1
  ln_apply_k<<<dim3(768,16),blk,0,stream>>>(x_tir,muS,rsS,lng,lnb,sAh,sAl,1);
  gemm3_k<0><<<dim3(128*6,1),blk,0,stream>>>(sAh,sAl,0,768, wh+589824,wl+589824,0,768, 768,128,768,786432, 0.f,
      b1, th,tl, nullptr, nullptr,nullptr,nullptr,nullptr,nullptr,nullptr);
  // f = LN(x_before) @ w2^T + b2  (batch-interleaved pair blocks)
  ln_apply_k<<<dim3(768,16),blk,0,stream>>>(x_bef,muS,rsS,lng,lnb,sAh,sAl,2);
  gemm3_k<0><<<dim3(128*6,1),blk,0,stream>>>(sAh,sAl,0,768, wh+2*589824,wl+2*589824,0,768, 768,128,768,1572864, 0.f,
      b2, fb,fb+786432, nullptr, nullptr,nullptr,nullptr,nullptr,nullptr,nullptr);

  // t^T per batch (into stageA — LN staging is dead now)
  tr_pairs_k<<<dim3(768,16),blk,0,stream>>>(th,tl,tTh,tTl);

  // attention in 2 chunks of 8 batches (S/P region = 32 MiB, in-place softmax)
  for (int c=0;c<2;c++){
    long cb = (long)c*8;
    // S = (r @ f^T) * scale  [8,1024,1024] fp32
    gemm3_k<1><<<dim3(8*8,8),blk,0,stream>>>(rh+cb*786432,rl+cb*786432,786432,768,
        fb+cb*1572864,fb+786432+cb*1572864,1572864,768,
        768,8,1024,1048576, SC, nullptr, nullptr,nullptr, Sf,
        nullptr,nullptr,nullptr,nullptr,nullptr,nullptr);
    // P = softmax(S) -> bf16 pairs, in place
    softmax_k<<<dim3(8192),blk,0,stream>>>(Sf);
    // mid = P @ t  [8,1024,768] fp32, overwriting f_b blocks
    gemm3_k<2><<<dim3(8*6,8),blk,0,stream>>>(Pu,Pu+1024,2097152,2048,
        tTh+cb*786432,tTl+cb*786432,786432,1024,
        1024,8,768,786432, 0.f, nullptr, nullptr,nullptr, midf+cb*786432,
        nullptr,nullptr,nullptr,nullptr,nullptr,nullptr);
  }

  // x_middle = (r+t) + reorder(mid)   (into SPx region — S/P dead)
  midtr_k<<<dim3(768,16),blk,0,stream>>>(midf,rh,rl,th,tl,xmf);
  // LN rows of x_middle -> pairs (into stageA — t^T dead)
  ln_rows_k<<<dim3(16384),blk,0,stream>>>(xmf,lng,lnb,xmh,xml);
  // out = (gelu(r+t)+gelu(r*t)) * (x_middle + LN(x_middle) @ wp^T + bp)
  gemm3_k<3><<<dim3(128*6,1),blk,0,stream>>>(xmh,xml,0,768, wh+3*589824,wl+3*589824,0,768,
      768,128,768,786432, 0.f, bp, nullptr,nullptr, nullptr, xmf, rh,rl,th,tl, out);
}

// Round 4
// 892.460 us; speedup vs baseline: 1.0323x; 1.0323x over previous
//
#include <hip/hip_runtime.h>
#include <hip/hip_bf16.h>
#include <math.h>

typedef unsigned short u16;
typedef __attribute__((ext_vector_type(8))) short bf16x8;
typedef __attribute__((ext_vector_type(4))) float f32x4;
typedef __attribute__((ext_vector_type(4))) u16 u16x4;

#define DEVI static __device__ __forceinline__

DEVI float bf2f(u16 h){ union{unsigned u; float f;} v; v.u=((unsigned)h)<<16; return v.f; }
DEVI u16 f2bf(float x){ union{float f; unsigned u;} v; v.f=x; unsigned r=v.u+0x7fffu+((v.u>>16)&1u); return (u16)(r>>16); }
DEVI void split2(float x, u16 &h, u16 &l){ h=f2bf(x); l=f2bf(x-bf2f(h)); }
DEVI float geluf(float x){ return 0.5f*x*(1.0f+erff(x*0.70710678118654752f)); }

#define GLD16(g,s) __builtin_amdgcn_global_load_lds((const __attribute__((address_space(1))) void*)(g), (__attribute__((address_space(3))) void*)(s), 16, 0, 0)

// ---- K0a: LN partial sums. block = 256 tokens x 96 channels, float4 loads along n ----
// sP/s2P layout: [inp][chunk 0..7][16384 tokens]
__global__ void ln_part_k(const float* __restrict__ x0, const float* __restrict__ x1,
                          const float* __restrict__ x2, float* __restrict__ sP,
                          float* __restrict__ s2P)
{
  const int inp = blockIdx.y;
  const float* x = inp==0?x0:(inp==1?x1:x2);
  const int tile = blockIdx.x>>3, chunk = blockIdx.x&7;
  const int T0 = tile*256;                 // 256 tokens, never straddles a batch
  const int b = T0>>10, n0 = T0&1023;
  const int tid = threadIdx.x, lane = tid&63, part = tid>>6;
  const float* base = x + ((size_t)b*768 + chunk*96)*1024 + n0 + lane*4;
  float4 s = {0,0,0,0}, s2 = {0,0,0,0};
  for (int c=part; c<96; c+=4){
    float4 v = *(const float4*)(base + (size_t)c*1024);
    s.x+=v.x; s.y+=v.y; s.z+=v.z; s.w+=v.w;
    s2.x+=v.x*v.x; s2.y+=v.y*v.y; s2.z+=v.z*v.z; s2.w+=v.w*v.w;
  }
  __shared__ float4 L1[4][64], L2[4][64];
  L1[part][lane]=s; L2[part][lane]=s2;
  __syncthreads();
  const float* f1=(const float*)L1; const float* f2=(const float*)L2;
  float a  = f1[tid]+f1[256+tid]+f1[512+tid]+f1[768+tid];
  float a2 = f2[tid]+f2[256+tid]+f2[512+tid]+f2[768+tid];
  long o = (long)inp*131072 + (long)chunk*16384 + T0 + tid;
  sP[o]=a; s2P[o]=a2;
}

// ---- K0b: finalize mu/rstd from 8 partials per token ----
__global__ void ln_fin_k(const float* __restrict__ sP, const float* __restrict__ s2P,
                         float* __restrict__ muS, float* __restrict__ rsS)
{
  int i = blockIdx.x*256+threadIdx.x;      // 0..49151
  int inp = i>>14, ti = i&16383;
  long base = (long)inp*131072 + ti;
  float s=0.f, s2=0.f;
  #pragma unroll
  for (int k=0;k<8;k++){ s += sP[base+(long)k*16384]; s2 += s2P[base+(long)k*16384]; }
  float mu = s*(1.f/768.f);
  float var = s2*(1.f/768.f)-mu*mu;
  muS[i]=mu; rsS[i]=rsqrtf(var+1e-5f);
}

// ------------- K1: apply LN + split to bf16 pairs + transpose [C,N] -> [N,C] -------------
__global__ void ln_apply_k(const float* __restrict__ x, const float* __restrict__ muS,
                           const float* __restrict__ rsS, const float* __restrict__ g,
                           const float* __restrict__ be, u16* __restrict__ Ah,
                           u16* __restrict__ Al, int inp)
{
  const int b = blockIdx.y;
  const int gx = blockIdx.x;               // 24 c-tiles x 32 n-tiles
  const int c0=(gx%24)*32, n0=(gx/24)*32;
  const int tid=threadIdx.x;
  __shared__ u16 Hh[32][33], Hl[32][33];
  const int nl=tid&31, cp=tid>>5;
  const int tok = b*1024 + n0 + nl;
  const float mu = muS[inp*16384+tok], rs = rsS[inp*16384+tok];
  #pragma unroll
  for (int i=0;i<4;i++){
    int cl = cp + i*8;
    int c = c0 + cl;
    float v = x[((size_t)(b*768+c))*1024 + n0 + nl];
    float y = (v-mu)*rs*g[c]+be[c];
    u16 h,l; split2(y,h,l);
    Hh[cl][nl]=h; Hl[cl][nl]=l;
  }
  __syncthreads();
  const int wn = tid>>3, wc=(tid&7)*4;
  u16x4 vh, vl;
  #pragma unroll
  for (int j=0;j<4;j++){ vh[j]=Hh[wc+j][wn]; vl[j]=Hl[wc+j][wn]; }
  size_t o = ((size_t)(b*1024+n0+wn))*768 + c0 + wc;
  *(u16x4*)(Ah+o)=vh; *(u16x4*)(Al+o)=vl;
}

// ---------------- weight split: fp32 [768,768] -> hi/lo bf16 ----------------
__global__ void wsplit_k(const float* __restrict__ w0,const float* __restrict__ w1,
                         const float* __restrict__ w2,const float* __restrict__ wpk,
                         u16* __restrict__ wh, u16* __restrict__ wl)
{
  const int ws = blockIdx.y;
  const float* w = ws==0?w0:(ws==1?w1:(ws==2?w2:wpk));
  int i = blockIdx.x*256+threadIdx.x;
  u16 h,l; split2(w[i],h,l);
  wh[(size_t)ws*589824+i]=h; wl[(size_t)ws*589824+i]=l;
}

// ------------- transpose t pairs: [B*1024,768] -> per-batch [768,1024] -------------
__global__ void tr_pairs_k(const u16* __restrict__ Sh, const u16* __restrict__ Sl,
                           u16* __restrict__ Dh, u16* __restrict__ Dl)
{
  const int b = blockIdx.y;
  const int gx = blockIdx.x;
  const int c0=(gx%24)*32, n0=(gx/24)*32;
  const int tid=threadIdx.x;
  __shared__ u16 Th[32][33], Tl[32][33];
  const int cl=tid&31, np=tid>>5;
  #pragma unroll
  for (int i=0;i<4;i++){
    int nl = np + i*8;
    size_t o = ((size_t)(b*1024+n0+nl))*768 + c0 + cl;
    Th[cl][nl]=Sh[o]; Tl[cl][nl]=Sl[o];
  }
  __syncthreads();
  const int nl2=tid&31, cp2=tid>>5;
  #pragma unroll
  for (int i=0;i<4;i++){
    int cl2 = cp2 + i*8;
    size_t o = ((size_t)b*786432) + (size_t)(c0+cl2)*1024 + n0 + nl2;
    Dh[o]=Th[cl2][nl2]; Dl[o]=Tl[cl2][nl2];
  }
}

// ---- softmax over rows of S chunk [8*1024, 1024] fp32, writing bf16 pairs IN PLACE ----
// out row layout: [row][ hi x1024 | lo x1024 ] u16  (same 4KiB as the fp32 row)
__global__ void softmax_k(float* __restrict__ S)
{
  const long row = blockIdx.x;
  const int tid=threadIdx.x;
  const int lane=tid&63, wid=tid>>6;
  float4 v4 = *(const float4*)(S + row*1024 + tid*4);
  float m = fmaxf(fmaxf(v4.x,v4.y),fmaxf(v4.z,v4.w));
  for (int o=1;o<64;o<<=1) m = fmaxf(m, __shfl_xor(m,o,64));
  __shared__ float red[4]; __shared__ float red2[4];
  if (lane==0) red[wid]=m;
  __syncthreads();
  m = fmaxf(fmaxf(red[0],red[1]),fmaxf(red[2],red[3]));
  float e0=__expf(v4.x-m), e1=__expf(v4.y-m), e2=__expf(v4.z-m), e3=__expf(v4.w-m);
  float s = e0+e1+e2+e3;
  for (int o=1;o<64;o<<=1) s += __shfl_xor(s,o,64);
  if (lane==0) red2[wid]=s;
  __syncthreads();                          // all S-row reads complete before this point
  s = red2[0]+red2[1]+red2[2]+red2[3];
  float inv = 1.f/s;
  u16x4 h4,l4;
  u16 h,l;
  split2(e0*inv,h,l); h4[0]=h; l4[0]=l;
  split2(e1*inv,h,l); h4[1]=h; l4[1]=l;
  split2(e2*inv,h,l); h4[2]=h; l4[2]=l;
  split2(e3*inv,h,l); h4[3]=h; l4[3]=l;
  u16* base = (u16*)S + row*2048;
  *(u16x4*)(base + tid*4)        = h4;
  *(u16x4*)(base + 1024 + tid*4) = l4;
}

// -------- row LN (contiguous C) + split -> xm pairs --------
__global__ void ln_rows_k(const float* __restrict__ x, const float* __restrict__ g,
                          const float* __restrict__ be, u16* __restrict__ Oh, u16* __restrict__ Ol)
{
  const long row=blockIdx.x;
  const int tid=threadIdx.x;
  const float* xr = x + row*768;
  float v0=xr[tid], v1=xr[tid+256], v2=xr[tid+512];
  float s=v0+v1+v2, s2=v0*v0+v1*v1+v2*v2;
  for (int o=1;o<64;o<<=1){ s+=__shfl_xor(s,o,64); s2+=__shfl_xor(s2,o,64); }
  __shared__ float rA[4]; __shared__ float rB[4];
  const int lane=tid&63, wid=tid>>6;
  if(lane==0){rA[wid]=s;rB[wid]=s2;}
  __syncthreads();
  s=rA[0]+rA[1]+rA[2]+rA[3]; s2=rB[0]+rB[1]+rB[2]+rB[3];
  float mu=s*(1.f/768.f), var=s2*(1.f/768.f)-mu*mu, rs=rsqrtf(var+1e-5f);
  u16 h,l;
  float y0=(v0-mu)*rs*g[tid]+be[tid];         split2(y0,h,l); Oh[row*768+tid]=h;     Ol[row*768+tid]=l;
  float y1=(v1-mu)*rs*g[tid+256]+be[tid+256]; split2(y1,h,l); Oh[row*768+tid+256]=h; Ol[row*768+tid+256]=l;
  float y2=(v2-mu)*rs*g[tid+512]+be[tid+512]; split2(y2,h,l); Oh[row*768+tid+512]=h; Ol[row*768+tid+512]=l;
}

// ---------------- 3-term split-fp32 GEMM: D = (Ah+Al)·(Bh+Bl)^T, 128x128 tile ----------------
// A: rows k-contig with row stride lda; B: rows k-contig with row stride ldb (elems).
// EPI: 0 = pairs+bias, 1 = f32*scale, 2 = f32, 3 = final fused epilogue -> dout,
//      4 = x_middle fuse: outF[b*oBat + cc*1024 + r] = v + (r+t)[same]   (PV + reorder + x_sum)
template<int EPI>
__launch_bounds__(256,2)
__global__ void gemm3_k(const u16* __restrict__ Ah, const u16* __restrict__ Al, long aBat, int lda,
                        const u16* __restrict__ Bh, const u16* __restrict__ Bl, long bBat, int ldb,
                        int K, int tilesM, int ldo, long oBat, float scaleV,
                        const float* __restrict__ bias,
                        u16* __restrict__ Oh, u16* __restrict__ Ol,
                        float* __restrict__ outF,
                        const float* __restrict__ xmid,
                        const u16* __restrict__ rhp, const u16* __restrict__ rlp,
                        const u16* __restrict__ thp, const u16* __restrict__ tlp,
                        float* __restrict__ dout)
{
  __shared__ u16 sm[16384];                // Ah|Al|Bh|Bl, each 128x32 bf16
  u16* sAh=sm; u16* sAl=sm+4096; u16* sBh=sm+8192; u16* sBl=sm+12288;
  const int tid=threadIdx.x, lane=tid&63, wid=tid>>6;
  const int wm=(wid&1)*64, wn=(wid>>1)*64;
  const int tm = (blockIdx.x % tilesM)*128;
  const int tn = (blockIdx.x / tilesM)*128;
  const int batch = blockIdx.y;
  const u16* gAh = Ah + (long)batch*aBat + (long)tm*lda;
  const u16* gAl = Al + (long)batch*aBat + (long)tm*lda;
  const u16* gBh = Bh + (long)batch*bBat + (long)tn*ldb;
  const u16* gBl = Bl + (long)batch*bBat + (long)tn*ldb;
  f32x4 acc[4][4];
  #pragma unroll
  for(int i=0;i<4;i++)
    #pragma unroll
    for(int j=0;j<4;j++) acc[i][j]=(f32x4){0.f,0.f,0.f,0.f};
  const int frow=lane&15, fko=(lane>>4)<<3;
  const int nkt=K>>5;
  for(int kt=0;kt<nkt;kt++){
    const int k0=kt<<5;
    __syncthreads();
    #pragma unroll
    for(int is=0;is<2;is++){
      int idx=is*256+tid;
      int mm=idx>>2, ko=(idx&3)<<3;
      long goA=(long)mm*lda + k0 + ko;
      long goB=(long)mm*ldb + k0 + ko;
      int so=(idx & ~63)*8;                // wave-uniform LDS base (ushorts)
      GLD16(gAh+goA, sAh+so);
      GLD16(gAl+goA, sAl+so);
      GLD16(gBh+goB, sBh+so);
      GLD16(gBl+goB, sBl+so);
    }
    __syncthreads();
    bf16x8 fbh[4], fbl[4];
    #pragma unroll
    for(int j=0;j<4;j++){
      int off=(wn+j*16+frow)*32+fko;
      fbh[j]=*(const bf16x8*)(sBh+off);
      fbl[j]=*(const bf16x8*)(sBl+off);
    }
    #pragma unroll
    for(int i=0;i<4;i++){
      int off=(wm+i*16+frow)*32+fko;
      bf16x8 fah=*(const bf16x8*)(sAh+off);
      bf16x8 fal=*(const bf16x8*)(sAl+off);
      #pragma unroll
      for(int j=0;j<4;j++){
        acc[i][j]=__builtin_amdgcn_mfma_f32_16x16x32_bf16(fah,fbh[j],acc[i][j],0,0,0);
        acc[i][j]=__builtin_amdgcn_mfma_f32_16x16x32_bf16(fah,fbl[j],acc[i][j],0,0,0);
        acc[i][j]=__builtin_amdgcn_mfma_f32_16x16x32_bf16(fal,fbh[j],acc[i][j],0,0,0);
      }
    }
  }
  const int r0 = tm+wm+((lane>>4)<<2);
  const int c0 = tn+wn+(lane&15);
  #pragma unroll
  for(int i=0;i<4;i++){
    #pragma unroll
    for(int q=0;q<4;q++){
      int r = r0 + i*16 + q;
      #pragma unroll
      for(int j=0;j<4;j++){
        int cc = c0 + j*16;
        float v = acc[i][j][q];
        if constexpr (EPI==4){
          long o2 = (long)batch*oBat + (long)cc*1024 + (r&1023);
          float rv = bf2f(rhp[o2])+bf2f(rlp[o2]);
          float tv = bf2f(thp[o2])+bf2f(tlp[o2]);
          outF[o2] = (rv+tv)+v;
        } else {
          long o = (long)batch*oBat + (long)(r>>10)*oBat + (long)(r&1023)*ldo + cc;
          if constexpr (EPI==0){
            v += bias[cc];
            u16 h,l; split2(v,h,l);
            Oh[o]=h; Ol[o]=l;
          } else if constexpr (EPI==1){
            outF[o] = v*scaleV;
          } else if constexpr (EPI==2){
            outF[o] = v;
          } else {
            float lin = v + bias[cc];
            float xmv = xmid[o];
            float rv = bf2f(rhp[o])+bf2f(rlp[o]);
            float tv = bf2f(thp[o])+bf2f(tlp[o]);
            float xs=rv+tv, xmu=rv*tv;
            dout[o] = (geluf(xs)+geluf(xmu))*(xmv+lin);
          }
        }
      }
    }
  }
}

extern "C" void kernel_launch(void* const* d_in, const int* in_sizes, int n_in,
                              void* d_out, int out_size, void* d_ws, size_t ws_size,
                              hipStream_t stream)
{
  const float* x_rgb=(const float*)d_in[0];
  const float* x_tir=(const float*)d_in[1];
  const float* x_bef=(const float*)d_in[2];
  const float* w0=(const float*)d_in[3];
  const float* b0=(const float*)d_in[4];
  const float* w1=(const float*)d_in[5];
  const float* b1=(const float*)d_in[6];
  const float* w2=(const float*)d_in[7];
  const float* b2=(const float*)d_in[8];
  const float* lng=(const float*)d_in[9];
  const float* lnb=(const float*)d_in[10];
  const float* wpk=(const float*)d_in[11];
  const float* bp=(const float*)d_in[12];
  float* out=(float*)d_out;

  char* wsb=(char*)d_ws;
  size_t off=0;
  auto alloc=[&](size_t bytes)->char*{ char* p=wsb+off; off=(off+bytes+255)&~(size_t)255; return p; };

  const long PAIRE = (long)16384*768;             // elements per bf16 plane (24 MiB)
  float* muS = (float*)alloc(3*16384*4);
  float* rsS = (float*)alloc(3*16384*4);
  float* sP  = (float*)alloc((size_t)3*8*16384*4);   // 1.5 MiB partial sums
  float* s2P = (float*)alloc((size_t)3*8*16384*4);
  u16* wh = (u16*)alloc(4*589824*2);
  u16* wl = (u16*)alloc(4*589824*2);
  // stageA (48 MiB): LN-staging pairs -> t^T pairs -> LN(x_middle) pairs
  char* stageA = alloc((size_t)2*PAIRE*2);
  u16* sAh=(u16*)stageA;      u16* sAl=sAh+PAIRE;
  u16* tTh=sAh;               u16* tTl=sAh+PAIRE;
  u16* xmh=sAh;               u16* xml=sAh+PAIRE;
  u16* rh=(u16*)alloc(PAIRE*2); u16* rl=(u16*)alloc(PAIRE*2);
  u16* th=(u16*)alloc(PAIRE*2); u16* tl=(u16*)alloc(PAIRE*2);
  // f/mid (48 MiB): batch-interleaved {fh_b, fl_b} pairs -> x_middle fp32 per batch, in place
  char* fmid = alloc((size_t)2*PAIRE*2);
  u16* fb=(u16*)fmid;
  float* midf=(float*)fmid;                       // x_middle: [b][c*1024+n] fp32, 3 MiB/batch
  // S/P chunk (32 MiB): S fp32 -> P pairs in place
  char* SPx = alloc((size_t)8*1024*1024*4);
  float* Sf=(float*)SPx;
  u16* Pu=(u16*)SPx;

  if (off > ws_size){                              // workspace too small: fail cleanly
    hipMemsetAsync(d_out, 0, (size_t)out_size*4, stream);
    return;
  }

  const float SC = 0.03608439182435161f;          // 1/sqrt(768)
  dim3 blk(256);

  wsplit_k<<<dim3(2304,4),blk,0,stream>>>(w0,w1,w2,wpk,wh,wl);
  ln_part_k<<<dim3(512,3),blk,0,stream>>>(x_rgb,x_tir,x_bef,sP,s2P);
  ln_fin_k<<<dim3(192),blk,0,stream>>>(sP,s2P,muS,rsS);

  // r = LN(x_rgb) @ w0^T + b0        [16384,768] pairs
  ln_apply_k<<<dim3(768,16),blk,0,stream>>>(x_rgb,muS,rsS,lng,lnb,sAh,sAl,0);
  gemm3_k<0><<<dim3(128*6,1),blk,0,stream>>>(sAh,sAl,0,768, wh,wl,0,768, 768,128,768,786432, 0.f,
      b0, rh,rl, nullptr, nullptr,nullptr,nullptr,nullptr,nullptr,nullptr);
  // t = LN(x_tir) @ w1^T + b1
  ln_apply_k<<<dim3(768,16),blk,0,stream>>>(x_tir,muS,rsS,lng,lnb,sAh,sAl,1);
  gemm3_k<0><<<dim3(128*6,1),blk,0,stream>>>(sAh,sAl,0,768, wh+589824,wl+589824,0,768, 768,128,768,786432, 0.f,
      b1, th,tl, nullptr, nullptr,nullptr,nullptr,nullptr,nullptr,nullptr);
  // f = LN(x_before) @ w2^T + b2  (batch-interleaved pair blocks in fmid region)
  ln_apply_k<<<dim3(768,16),blk,0,stream>>>(x_bef,muS,rsS,lng,lnb,sAh,sAl,2);
  gemm3_k<0><<<dim3(128*6,1),blk,0,stream>>>(sAh,sAl,0,768, wh+2*589824,wl+2*589824,0,768, 768,128,768,1572864, 0.f,
      b2, fb,fb+786432, nullptr, nullptr,nullptr,nullptr,nullptr,nullptr,nullptr);

  // t^T per batch (into stageA — LN staging is dead now)
  tr_pairs_k<<<dim3(768,16),blk,0,stream>>>(th,tl,tTh,tTl);

  // attention in 2 chunks of 8 batches (S/P region = 32 MiB, in-place softmax)
  for (int c=0;c<2;c++){
    long cb = (long)c*8;
    // S = (r @ f^T) * scale  [8,1024,1024] fp32
    gemm3_k<1><<<dim3(8*8,8),blk,0,stream>>>(rh+cb*786432,rl+cb*786432,786432,768,
        fb+cb*1572864,fb+786432+cb*1572864,1572864,768,
        768,8,1024,1048576, SC, nullptr, nullptr,nullptr, Sf,
        nullptr,nullptr,nullptr,nullptr,nullptr,nullptr);
    // P = softmax(S) -> bf16 pairs, in place
    softmax_k<<<dim3(8192),blk,0,stream>>>(Sf);
    // x_middle = (P @ t reordered) + (r+t), written channel-major into dead f blocks
    gemm3_k<4><<<dim3(8*6,8),blk,0,stream>>>(Pu,Pu+1024,2097152,2048,
        tTh+cb*786432,tTl+cb*786432,786432,1024,
        1024,8,1024,786432, 0.f, nullptr, nullptr,nullptr, midf+cb*786432,
        nullptr, rh+cb*786432,rl+cb*786432, th+cb*786432,tl+cb*786432, nullptr);
  }

  // LN rows of x_middle -> pairs (into stageA — t^T dead)
  ln_rows_k<<<dim3(16384),blk,0,stream>>>(midf,lng,lnb,xmh,xml);
  // out = (gelu(r+t)+gelu(r*t)) * (x_middle + LN(x_middle) @ wp^T + bp)
  gemm3_k<3><<<dim3(128*6,1),blk,0,stream>>>(xmh,xml,0,768, wh+3*589824,wl+3*589824,0,768,
      768,128,768,786432, 0.f, bp, nullptr,nullptr, nullptr, midf, rh,rl,th,tl, out);
}